// Round 11
// baseline (217.607 us; speedup 1.0000x reference)
//
#include <hip/hip_runtime.h>

// B=4, C=256, H=W=64, O=256, K=3, PAD=2, DIL=2; offset conv: 18ch 3x3 p1 d1.
// R11: (1) deform split over M (grid z=2, 128 o/block, 256 thr) with
// single-buffered x window -> LDS ~59KB -> 2 blocks/CU (R10 was 1 block/CU,
// 50% idle on barrier critical path). In-place restage at cb boundary:
// reg-prefetch n==6, commit + lone-sample after n==8's barrier.
// (2) offset conv -> band kernel: stage 6x66x32ch with per-(ch,row) threads
// doing 16 contiguous float4 loads (R10's 16KB-stride scatter was the ~80us
// mystery), direct b128 B-frags, atomic partials, 512 blocks.
// K order k = cb*576 + n*64 + cl; all frag layouts R7-R10-verified.

typedef __attribute__((ext_vector_type(8))) short short8;
typedef __attribute__((ext_vector_type(4))) float floatx4;

__device__ inline unsigned short f2bf(float f) {  // RNE fp32 -> bf16 bits
  unsigned int u = __float_as_uint(f);
  u += 0x7fff + ((u >> 16) & 1);
  return (unsigned short)(u >> 16);
}
__device__ inline float bflo(unsigned int u) { return __uint_as_float(u << 16); }
__device__ inline float bfhi(unsigned int u) {
  return __uint_as_float(u & 0xffff0000u);
}

// ---------------------------------------------------------------------------
// prep (unchanged, R7/R8-verified).
// wfrag:  [ci=36][mt=16][kt=2][lane=64][j=8], val = dw[o=mt*16+(lane&15)]
//         [c*9+n], c = cb*64+kt*32+(lane>>4)*8+j, cb=ci/9, n=ci%9.
// wfragA: [ci=36][kt=2][mt=2][lane=64][j=8], val = (o<18)?ow[o][c*9+t]:0.
// ---------------------------------------------------------------------------
__global__ __launch_bounds__(256) void prep_kernel(
    const float* __restrict__ dw, const float* __restrict__ ow,
    unsigned short* __restrict__ wfrag, unsigned short* __restrict__ wfragA) {
  int idx = blockIdx.x * 256 + threadIdx.x;
  if (idx < 73728) {
    int ci = idx >> 11;
    int mt = (idx >> 7) & 15;
    int kt = (idx >> 6) & 1;
    int lane = idx & 63;
    int cb = ci / 9, n = ci - cb * 9;
    int o = mt * 16 + (lane & 15);
    int cbase = cb * 64 + kt * 32 + (lane >> 4) * 8;
    short8 v;
#pragma unroll
    for (int j = 0; j < 8; ++j)
      v[j] = (short)f2bf(dw[o * 2304 + (cbase + j) * 9 + n]);
    *((short8*)wfrag + idx) = v;
  } else {
    int e = idx - 73728;
    if (e < 9216) {
      int ci = e >> 8;
      int kt = (e >> 7) & 1;
      int mt = (e >> 6) & 1;
      int lane = e & 63;
      int cb = ci / 9, t = ci - cb * 9;
      int o = mt * 16 + (lane & 15);
      int cbase = cb * 64 + kt * 32 + (lane >> 4) * 8;
      short8 v;
      if (o < 18) {
#pragma unroll
        for (int j = 0; j < 8; ++j)
          v[j] = (short)f2bf(ow[o * 2304 + (cbase + j) * 9 + t]);
      } else {
        v = (short8)0;
      }
      *((short8*)wfragA + e) = v;
    }
  }
}

// ---------------------------------------------------------------------------
// Offset conv via MFMA, band form: grid (16 bands, 4 b, 8 cg) = 512 blocks.
// Block = 4 full-width rows x 32 channels. Stage 6 rows x 66 cols (halo +-1,
// zero ends) x 32 ch in octet layout [pos=ry*66+cx][32ch]; thread = (ch,row)
// -> 16 CONTIGUOUS float4 loads (coalesced; fixes R10's strided scatter).
// Conv: wave wv covers n-tiles wv*4..+3; B-frag = one ds_read_b128; A JIT.
// atomicAdd fp32 partials to off_buf (zeroed per launch).
// ---------------------------------------------------------------------------
__global__ __launch_bounds__(256) void offset_conv_band(
    const float* __restrict__ x, const unsigned short* __restrict__ wfragA,
    float* __restrict__ off_buf) {
  int tid = threadIdx.x;
  int band = blockIdx.x, b = blockIdx.y, cg = blockIdx.z;
  int lane = tid & 63, wv = tid >> 6;

  __shared__ unsigned short s_bd[396 * 32];  // [pos=ry*66+cx][32 ch]

  const float* xb = x + (size_t)b * 256 * 4096;

  if (tid < 192) {
    int ch = tid / 6, ry = tid - ch * 6;
    int gy = band * 4 - 1 + ry;
    bool oky = (gy >= 0 && gy < 64);
    const float* src = xb + (size_t)(cg * 32 + ch) * 4096 + gy * 64;
    unsigned short* dst = s_bd + ch;
    int rowbase = ry * 66 * 32;
    dst[rowbase] = 0;
    dst[rowbase + 65 * 32] = 0;
#pragma unroll 4
    for (int g16 = 0; g16 < 16; ++g16) {
      float4 v = oky ? *(const float4*)(src + g16 * 4)
                     : make_float4(0.f, 0.f, 0.f, 0.f);
      dst[rowbase + (g16 * 4 + 1) * 32] = f2bf(v.x);
      dst[rowbase + (g16 * 4 + 2) * 32] = f2bf(v.y);
      dst[rowbase + (g16 * 4 + 3) * 32] = f2bf(v.z);
      dst[rowbase + (g16 * 4 + 4) * 32] = f2bf(v.w);
    }
  }
  __syncthreads();

  int col = lane & 15, kq = lane >> 4;
  int cb = cg >> 1, ckt = cg & 1;
  const short8* wA = (const short8*)wfragA;

  floatx4 acc[4][2];
#pragma unroll
  for (int i = 0; i < 4; ++i) {
    acc[i][0] = (floatx4)(0.f);
    acc[i][1] = (floatx4)(0.f);
  }

#pragma unroll
  for (int t = 0; t < 9; ++t) {
    int ci = cb * 9 + t;
    int ty = t / 3, tx = t - ty * 3;
    short8 a0 = wA[((ci * 2 + ckt) * 2 + 0) * 64 + lane];
    short8 a1 = wA[((ci * 2 + ckt) * 2 + 1) * 64 + lane];
#pragma unroll
    for (int nt = 0; nt < 4; ++nt) {
      int px = (wv * 4 + nt) * 16 + col;
      int r0 = px >> 6, gx = px & 63;
      int pos = (r0 + ty) * 66 + gx + tx;  // cx = (gx-1+tx)+1
      short8 bfr = *(const short8*)&s_bd[pos * 32 + kq * 8];
      acc[nt][0] =
          __builtin_amdgcn_mfma_f32_16x16x32_bf16(a0, bfr, acc[nt][0], 0, 0, 0);
      acc[nt][1] =
          __builtin_amdgcn_mfma_f32_16x16x32_bf16(a1, bfr, acc[nt][1], 0, 0, 0);
    }
  }

  // epilogue: atomic partial sums, o<18 (R10-verified mapping)
  int quad = lane >> 4;
#pragma unroll
  for (int nt = 0; nt < 4; ++nt) {
    int pp2 = (wv * 4 + nt) * 16 + col;
    int hh = band * 4 + (pp2 >> 6), ww = pp2 & 63;
#pragma unroll
    for (int mt = 0; mt < 2; ++mt)
#pragma unroll
      for (int r = 0; r < 4; ++r) {
        int o = mt * 16 + quad * 4 + r;
        if (o < 18)
          atomicAdd(&off_buf[(((size_t)b * 18 + o) * 64 + hh) * 64 + ww],
                    acc[nt][mt][r]);
      }
  }
}

// ---------------------------------------------------------------------------
// Sampler (R9/R10-verified): item = (px, oct). 4 corner ds_read_b128 (8 ch)
// -> bilinear -> truncate-bf16 -> one ds_write_b128 at XOR-swizzled colf
// slot. kl == cl = oct*8+j.
// ---------------------------------------------------------------------------
__device__ __forceinline__ void sample_chunk8(
    const unsigned short* __restrict__ sx, int n,
    unsigned short* __restrict__ colf, int px, int oct,
    const float (*sw4)[64][4], const short (*scoff)[64]) {
  float4 wq = *(const float4*)&sw4[n][px][0];
  const unsigned short* p = sx + (int)scoff[n][px] * 72 + oct * 8;
  uint4 c00 = *(const uint4*)(p);
  uint4 c01 = *(const uint4*)(p + 72);
  uint4 c10 = *(const uint4*)(p + 15 * 72);
  uint4 c11 = *(const uint4*)(p + 16 * 72);
  const unsigned int* u00 = (const unsigned int*)&c00;
  const unsigned int* u01 = (const unsigned int*)&c01;
  const unsigned int* u10 = (const unsigned int*)&c10;
  const unsigned int* u11 = (const unsigned int*)&c11;
  uint4 outv;
  unsigned int* op = (unsigned int*)&outv;
#pragma unroll
  for (int q = 0; q < 4; ++q) {
    float lo = wq.x * bflo(u00[q]) + wq.y * bflo(u01[q]) +
               wq.z * bflo(u10[q]) + wq.w * bflo(u11[q]);
    float hi = wq.x * bfhi(u00[q]) + wq.y * bfhi(u01[q]) +
               wq.z * bfhi(u10[q]) + wq.w * bfhi(u11[q]);
    op[q] = (__float_as_uint(hi) & 0xffff0000u) | (__float_as_uint(lo) >> 16);
  }
  int idx = ((px >> 4) * 2 + (oct >> 2)) * 64 + ((oct & 3) << 4) + (px & 15);
  int slot = idx ^ ((idx >> 4) & 7);
  *(uint4*)&colf[slot * 8] = outv;
}

// ---------------------------------------------------------------------------
// Fused bilinear sample + bf16 MFMA GEMM, M-SPLIT. Grid (64,4,2) = 512
// blocks (2/CU), 256 thr (4 waves: oq = mh*2 + (wv>>1), nh = wv&1).
// x window single-buffered (LDS ~59KB); in-place restage at cb boundary.
// colf dbuf + XOR swizzle; one barrier per chunk (+2 at boundaries).
// ---------------------------------------------------------------------------
__global__ __launch_bounds__(256) void deform_kernel(
    const float* __restrict__ x, const float* __restrict__ off_buf,
    const float* __restrict__ obias, const unsigned short* __restrict__ wfrag,
    const float* __restrict__ bias, float* __restrict__ out) {
  int tid = threadIdx.x;
  int b = blockIdx.y, tile = blockIdx.x, mh = blockIdx.z;
  int h0 = (tile >> 3) * 8, w0 = (tile & 7) * 8;
  int lane = tid & 63, wv = tid >> 6;
  int oq = mh * 2 + (wv >> 1), nh = wv & 1;

  __shared__ unsigned short s_x8[225 * 72];  // single buffer, octet layout
  __shared__ __align__(16) unsigned short s_colf[2][4096];
  __shared__ __align__(16) float s_w4[9][64][4];
  __shared__ short s_coff[9][64];

  // phase 0 (R6/R8-verified): bias + clip fused; off_buf holds raw sums.
  for (int e = tid; e < 576; e += 256) {
    int n = e >> 6, pe = e & 63;
    int hy = h0 + (pe >> 3), wx = w0 + (pe & 7);
    float dy =
        off_buf[(((size_t)b * 18 + 2 * n) * 64 + hy) * 64 + wx] + obias[2 * n];
    float dx = off_buf[(((size_t)b * 18 + 2 * n + 1) * 64 + hy) * 64 + wx] +
               obias[2 * n + 1];
    dy = fminf(fmaxf(dy, -1.f), 1.f);
    dx = fminf(fmaxf(dx, -1.f), 1.f);
    float fy = dy + (float)(hy - 2 + (n / 3) * 2);
    float fx = dx + (float)(wx - 2 + (n % 3) * 2);
    float y0f = floorf(fy), x0f = floorf(fx);
    float wy1 = fy - y0f, wx1 = fx - x0f;
    float wy0 = 1.f - wy1, wx0 = 1.f - wx1;
    s_coff[n][pe] =
        (short)(((int)y0f - (h0 - 3)) * 15 + ((int)x0f - (w0 - 3)));
    s_w4[n][pe][0] = wy0 * wx0;
    s_w4[n][pe][1] = wy0 * wx1;
    s_w4[n][pe][2] = wy1 * wx0;
    s_w4[n][pe][3] = wy1 * wx1;
  }

  const float* xb = x + (size_t)b * 256 * 4096;
  // stage cb0 (direct)
  for (int e = tid; e < 1800; e += 256) {
    int oct = e / 225, pos = e - oct * 225;
    int ry = pos / 15, rx = pos - ry * 15;
    int gy = h0 - 3 + ry, gx = w0 - 3 + rx;
    bool ok = (gy >= 0 && gy < 64 && gx >= 0 && gx < 64);
    const float* p0 = xb + ((size_t)(oct * 8)) * 4096 + (ok ? gy * 64 + gx : 0);
    unsigned int s[8];
#pragma unroll
    for (int j = 0; j < 8; ++j)
      s[j] = ok ? (unsigned int)f2bf(p0[(size_t)j * 4096]) : 0u;
    uint4 v;
    v.x = s[0] | (s[1] << 16);
    v.y = s[2] | (s[3] << 16);
    v.z = s[4] | (s[5] << 16);
    v.w = s[6] | (s[7] << 16);
    *(uint4*)&s_x8[pos * 72 + oct * 8] = v;
  }
  __syncthreads();

  // prologue: sample chunk 0 -> colf[0] (items tid, tid+256)
  sample_chunk8(s_x8, 0, s_colf[0], tid >> 3, tid & 7, s_w4, s_coff);
  {
    int it = tid + 256;
    sample_chunk8(s_x8, 0, s_colf[0], it >> 3, it & 7, s_w4, s_coff);
  }
  __syncthreads();

  floatx4 acc[4][2];
#pragma unroll
  for (int i = 0; i < 4; ++i)
#pragma unroll
    for (int j = 0; j < 2; ++j) acc[i][j] = (floatx4)(0.f);

  uint4 pr[8];

  for (int cb = 0; cb < 4; ++cb) {
    for (int n = 0; n < 9; ++n) {
      int ci = cb * 9 + n;
      // A-frags for this block's 128 o (global/L2)
      short8 areg[2][4];
      const short8* wg = (const short8*)wfrag + (size_t)ci * 2048;
#pragma unroll
      for (int k2 = 0; k2 < 2; ++k2)
#pragma unroll
        for (int mi = 0; mi < 4; ++mi)
          areg[k2][mi] = wg[((oq * 4 + mi) * 2 + k2) * 64 + lane];

      // reg-prefetch cb+1 staging at n==6 (commit after n==8's barrier)
      if (n == 6 && cb < 3) {
#pragma unroll
        for (int u = 0; u < 8; ++u) {
          int e = tid + u * 256;
          pr[u] = make_uint4(0u, 0u, 0u, 0u);
          if (e < 1800) {
            int oct = e / 225, pos = e - oct * 225;
            int ry = pos / 15, rx = pos - ry * 15;
            int gy = h0 - 3 + ry, gx = w0 - 3 + rx;
            if (gy >= 0 && gy < 64 && gx >= 0 && gx < 64) {
              const float* p0 = xb +
                                ((size_t)((cb + 1) * 64 + oct * 8)) * 4096 +
                                gy * 64 + gx;
              unsigned int s[8];
#pragma unroll
              for (int j = 0; j < 8; ++j)
                s[j] = (unsigned int)f2bf(p0[(size_t)j * 4096]);
              pr[u].x = s[0] | (s[1] << 16);
              pr[u].y = s[2] | (s[3] << 16);
              pr[u].z = s[4] | (s[5] << 16);
              pr[u].w = s[6] | (s[7] << 16);
            }
          }
        }
      }

      // sample chunk ci+1 (same cb window) for n<8
      if (n < 8) {
        sample_chunk8(s_x8, n + 1, s_colf[(ci + 1) & 1], tid >> 3, tid & 7,
                      s_w4, s_coff);
        int it = tid + 256;
        sample_chunk8(s_x8, n + 1, s_colf[(ci + 1) & 1], it >> 3, it & 7,
                      s_w4, s_coff);
      }

      // MFMA chunk ci from colf[ci&1] (slot-swizzled reads)
      const unsigned short* cf = s_colf[ci & 1];
#pragma unroll
      for (int k2 = 0; k2 < 2; ++k2) {
        short8 bfr[2];
#pragma unroll
        for (int tn = 0; tn < 2; ++tn) {
          int idx = ((nh * 2 + tn) * 2 + k2) * 64 + lane;
          int slot = idx ^ ((idx >> 4) & 7);
          bfr[tn] = *(const short8*)&cf[slot * 8];
        }
#pragma unroll
        for (int mi = 0; mi < 4; ++mi)
#pragma unroll
          for (int tn = 0; tn < 2; ++tn)
            acc[mi][tn] = __builtin_amdgcn_mfma_f32_16x16x32_bf16(
                areg[k2][mi], bfr[tn], acc[mi][tn], 0, 0, 0);
      }
      __syncthreads();

      // cb boundary: commit new window, then lone-sample (cb+1, n=0)
      if (n == 8 && cb < 3) {
#pragma unroll
        for (int u = 0; u < 8; ++u) {
          int e = tid + u * 256;
          if (e < 1800) {
            int oct = e / 225, pos = e - oct * 225;
            *(uint4*)&s_x8[pos * 72 + oct * 8] = pr[u];
          }
        }
        __syncthreads();
        sample_chunk8(s_x8, 0, s_colf[(ci + 1) & 1], tid >> 3, tid & 7, s_w4,
                      s_coff);
        int it = tid + 256;
        sample_chunk8(s_x8, 0, s_colf[(ci + 1) & 1], it >> 3, it & 7, s_w4,
                      s_coff);
        __syncthreads();
      }
    }
  }

  // epilogue (R5-verified): C/D col=lane&15, row=quad*4+r
  int quad = lane >> 4, col = lane & 15;
#pragma unroll
  for (int mi = 0; mi < 4; ++mi)
#pragma unroll
    for (int tn = 0; tn < 2; ++tn) {
      int pxo = (nh * 2 + tn) * 16 + col;
      int h = h0 + (pxo >> 3), w = w0 + (pxo & 7);
#pragma unroll
      for (int r = 0; r < 4; ++r) {
        int o = oq * 64 + mi * 16 + quad * 4 + r;
        out[(((size_t)b * 256 + o) * 64 + h) * 64 + w] =
            acc[mi][tn][r] + bias[o];
      }
    }
}

extern "C" void kernel_launch(void* const* d_in, const int* in_sizes, int n_in,
                              void* d_out, int out_size, void* d_ws,
                              size_t ws_size, hipStream_t stream) {
  (void)in_sizes; (void)n_in; (void)out_size; (void)ws_size;
  const float* x        = (const float*)d_in[0];  // (4,256,64,64)
  const float* offset_w = (const float*)d_in[1];  // (18,256,3,3)
  const float* offset_b = (const float*)d_in[2];  // (18,)
  const float* deform_w = (const float*)d_in[3];  // (256,256,3,3)
  const float* deform_b = (const float*)d_in[4];  // (256,)
  float* out = (float*)d_out;

  float* off_buf = (float*)d_ws;                                // 294912 f
  unsigned short* wfrag = (unsigned short*)(off_buf + 294912);  // 589824 bf16
  unsigned short* wfragA = wfrag + 589824;                      // 73728 bf16

  hipMemsetAsync(off_buf, 0, 294912 * sizeof(float), stream);
  prep_kernel<<<324, 256, 0, stream>>>(deform_w, offset_w, wfrag, wfragA);
  offset_conv_band<<<dim3(16, 4, 8), 256, 0, stream>>>(x, wfragA, off_buf);
  deform_kernel<<<dim3(64, 4, 2), 256, 0, stream>>>(x, off_buf, offset_b,
                                                    wfrag, deform_b, out);
  hipMemcpyAsync(out + 4194304, deform_w, 589824 * sizeof(float),
                 hipMemcpyDeviceToDevice, stream);
}

// Round 14
// 181.776 us; speedup vs baseline: 1.1971x; 1.1971x over previous
//
#include <hip/hip_runtime.h>

// B=4, C=256, H=W=64, O=256, K=3, PAD=2, DIL=2; offset conv: 18ch 3x3 p1 d1.
// R13 = R8's deform + prep RESTORED VERBATIM (R12's NaN was a transcription
// bug: s_xp shrunk to 1440 while the sampler indexes 7680) + R12's
// massively-parallel pure-VALU offset conv (512 blocks, weights-only LDS,
// coalesced taps, fp32 atomic partials).

typedef __attribute__((ext_vector_type(8))) short short8;
typedef __attribute__((ext_vector_type(4))) float floatx4;

__device__ inline unsigned short f2bf(float f) {  // RNE fp32 -> bf16 bits
  unsigned int u = __float_as_uint(f);
  u += 0x7fff + ((u >> 16) & 1);
  return (unsigned short)(u >> 16);
}
__device__ inline float bflo(unsigned int u) { return __uint_as_float(u << 16); }
__device__ inline float bfhi(unsigned int u) {
  return __uint_as_float(u & 0xffff0000u);
}

// ---------------------------------------------------------------------------
// prep (R7/R8-verified, wfrag only):
// wfrag: [ci=36][mt=16][kt=2][lane=64][j=8], val = dw[o=mt*16+(lane&15)]
//        [c*9+n], c = cb*64+kt*32+(lane>>4)*8+j, cb=ci/9, n=ci%9.
// ---------------------------------------------------------------------------
__global__ __launch_bounds__(256) void prep_kernel(
    const float* __restrict__ dw, unsigned short* __restrict__ wfrag) {
  int idx = blockIdx.x * 256 + threadIdx.x;
  int ci = idx >> 11;
  int mt = (idx >> 7) & 15;
  int kt = (idx >> 6) & 1;
  int lane = idx & 63;
  int cb = ci / 9, n = ci - cb * 9;
  int o = mt * 16 + (lane & 15);
  int cbase = cb * 64 + kt * 32 + (lane >> 4) * 8;
  short8 v;
#pragma unroll
  for (int j = 0; j < 8; ++j)
    v[j] = (short)f2bf(dw[o * 2304 + (cbase + j) * 9 + n]);
  *((short8*)wfrag + idx) = v;
}

// ---------------------------------------------------------------------------
// Offset conv, pure VALU, massively parallel: grid (16 bands, 4 b, 8 cg) =
// 512 blocks. Thread = one pixel of a 4-row band; 32 channels per block.
// Weights staged once to LDS as [ch][t][o=18]; x taps from global, coalesced
// per tap (lane = w), rows L1-reused. fp32 atomicAdd raw partials into
// off_buf (zeroed per launch); deform phase 0 applies bias + clip.
// ---------------------------------------------------------------------------
__global__ __launch_bounds__(256) void offset_conv_valu(
    const float* __restrict__ x, const float* __restrict__ ow,
    float* __restrict__ off_buf) {
  int tid = threadIdx.x;
  int band = blockIdx.x, b = blockIdx.y, cg = blockIdx.z;
  int r0 = tid >> 6, w = tid & 63;
  int h = band * 4 + r0;

  __shared__ __align__(16) float s_w2[32 * 162];  // [ch][t*18+o]

  for (int e = tid; e < 5184; e += 256) {
    int ch = e / 162, rem = e - ch * 162;
    int t = rem / 18, o = rem - t * 18;
    s_w2[e] = ow[o * 2304 + cg * 288 + ch * 9 + t];
  }
  __syncthreads();

  float acc[18];
#pragma unroll
  for (int i = 0; i < 18; ++i) acc[i] = 0.f;

  const float* xc = x + ((size_t)b * 256 + cg * 32) * 4096;
  for (int ch = 0; ch < 32; ++ch) {
    const float* xp = xc + (size_t)ch * 4096;
    float xv[9];
#pragma unroll
    for (int ty = 0; ty < 3; ++ty) {
      int gy = h - 1 + ty;
      bool oky = ((unsigned)gy < 64u);
#pragma unroll
      for (int tx = 0; tx < 3; ++tx) {
        int gx = w - 1 + tx;
        bool ok = oky && ((unsigned)gx < 64u);
        xv[ty * 3 + tx] = ok ? xp[gy * 64 + gx] : 0.f;
      }
    }
    const float* wc = &s_w2[ch * 162];
#pragma unroll
    for (int t = 0; t < 9; ++t) {
#pragma unroll
      for (int o2 = 0; o2 < 9; ++o2) {
        float2 w2 = *(const float2*)(wc + t * 18 + o2 * 2);  // 8B-aligned
        acc[o2 * 2] += xv[t] * w2.x;
        acc[o2 * 2 + 1] += xv[t] * w2.y;
      }
    }
  }

#pragma unroll
  for (int o = 0; o < 18; ++o)
    atomicAdd(&off_buf[(((size_t)b * 18 + o) * 64 + h) * 64 + w], acc[o]);
}

// ---------------------------------------------------------------------------
// Deform sampler (R8-verified): thread = (oct = wave, px = lane).
// 8 consecutive cl = 4 pair-planes (oct*960 base, 240 per plane); 16 corner
// u32 reads -> short8 -> one ds_write_b128 into colf. kl == cl = oct*8+j.
// ---------------------------------------------------------------------------
__device__ __forceinline__ void sample_chunk(
    const unsigned int* __restrict__ xpcb, int n,
    unsigned short* __restrict__ colf, int oct, int px,
    const float (*sw4)[64][4], const int (*scoff)[64]) {
  float4 wq = *(const float4*)&sw4[n][px][0];
  const unsigned int* bp = xpcb + oct * 960 + scoff[n][px];
  unsigned int ua[4], ub[4], uc[4], ud[4];
#pragma unroll
  for (int q = 0; q < 4; ++q) {
    const unsigned int* pl = bp + q * 240;
    ua[q] = pl[0];
    ub[q] = pl[1];
    uc[q] = pl[16];
    ud[q] = pl[17];
  }
  short8 v8;
#pragma unroll
  for (int q = 0; q < 4; ++q) {
    float lo = wq.x * bflo(ua[q]) + wq.y * bflo(ub[q]) + wq.z * bflo(uc[q]) +
               wq.w * bflo(ud[q]);
    float hi = wq.x * bfhi(ua[q]) + wq.y * bfhi(ub[q]) + wq.z * bfhi(uc[q]) +
               wq.w * bfhi(ud[q]);
    v8[2 * q] = (short)(__float_as_uint(lo) >> 16);
    v8[2 * q + 1] = (short)(__float_as_uint(hi) >> 16);
  }
  int nt = px >> 4, kt = oct >> 2, qk = oct & 3;
  *(short8*)&colf[((nt * 2 + kt) * 64 + ((px & 15) | (qk << 4))) * 8] = v8;
}

// ---------------------------------------------------------------------------
// Fused bilinear sample + bf16 MFMA GEMM (R8-verified, restored verbatim).
// 8x8 px tile, 256 o, 512 thr (8 waves). Chunks (cb 0..3) x (n 0..8);
// x staged once per cb as 32 bf16-pair planes (s_xp[2][7680], dbuf,
// reg-prefetch n==6 / commit n==7); colf dbuf; ONE barrier per chunk.
// ---------------------------------------------------------------------------
__global__ __launch_bounds__(512) void deform_kernel(
    const float* __restrict__ x, const float* __restrict__ off_buf,
    const float* __restrict__ obias, const unsigned short* __restrict__ wfrag,
    const float* __restrict__ bias, float* __restrict__ out) {
  int tid = threadIdx.x;
  int b = blockIdx.y, tile = blockIdx.x;
  int h0 = (tile >> 3) * 8, w0 = (tile & 7) * 8;
  int lane = tid & 63, wv = tid >> 6;
  int oq = wv >> 1, nh = wv & 1;
  int oct = wv;

  __shared__ unsigned int s_xp[2][7680];  // [buf][plane*240 + ry*16 + rx]
  __shared__ __align__(16) unsigned short s_colf[2][4096];
  __shared__ __align__(16) float s_w4[9][64][4];
  __shared__ int s_coff[9][64];

  // phase 0 (R6/R8-verified): bias + clip fused; off_buf holds raw sums.
  for (int e = tid; e < 576; e += 512) {
    int n = e >> 6, pe = e & 63;
    int hy = h0 + (pe >> 3), wx = w0 + (pe & 7);
    float dy =
        off_buf[(((size_t)b * 18 + 2 * n) * 64 + hy) * 64 + wx] + obias[2 * n];
    float dx = off_buf[(((size_t)b * 18 + 2 * n + 1) * 64 + hy) * 64 + wx] +
               obias[2 * n + 1];
    dy = fminf(fmaxf(dy, -1.f), 1.f);
    dx = fminf(fmaxf(dx, -1.f), 1.f);
    float fy = dy + (float)(hy - 2 + (n / 3) * 2);
    float fx = dx + (float)(wx - 2 + (n % 3) * 2);
    float y0f = floorf(fy), x0f = floorf(fx);
    float wy1 = fy - y0f, wx1 = fx - x0f;
    float wy0 = 1.f - wy1, wx0 = 1.f - wx1;
    s_coff[n][pe] = ((int)y0f - (h0 - 3)) * 16 + ((int)x0f - (w0 - 3));
    s_w4[n][pe][0] = wy0 * wx0;
    s_w4[n][pe][1] = wy0 * wx1;
    s_w4[n][pe][2] = wy1 * wx0;
    s_w4[n][pe][3] = wy1 * wx1;
  }

  const float* xb = x + (size_t)b * 256 * 4096;
  // stage cb0 -> xp[0] (element-parallel, coalesced in rx)
  for (int e = tid; e < 7680; e += 512) {
    int pl = e / 240, pos = e - pl * 240;
    int ry = pos >> 4, rx = pos & 15;
    int gy = h0 - 3 + ry, gx = w0 - 3 + rx;
    bool ok = (rx < 15 && gy >= 0 && gy < 64 && gx >= 0 && gx < 64);
    const float* p0 = xb + (size_t)(pl * 2) * 4096;
    float v0 = ok ? p0[gy * 64 + gx] : 0.f;
    float v1 = ok ? p0[4096 + gy * 64 + gx] : 0.f;
    s_xp[0][e] = (unsigned int)f2bf(v0) | ((unsigned int)f2bf(v1) << 16);
  }
  __syncthreads();

  // prologue: sample chunk 0 (cb0, n0) -> colf[0]
  sample_chunk(s_xp[0], 0, s_colf[0], oct, lane, s_w4, s_coff);
  __syncthreads();

  floatx4 acc[4][2];
#pragma unroll
  for (int i = 0; i < 4; ++i)
#pragma unroll
    for (int j = 0; j < 2; ++j) acc[i][j] = (floatx4)(0.f);

  float pr0[15], pr1[15];

  for (int cb = 0; cb < 4; ++cb) {
    for (int n = 0; n < 9; ++n) {
      int ci = cb * 9 + n;
      // A-frags for chunk ci (global/L2; consumed at MFMA below)
      short8 areg[2][4];
      const short8* wg = (const short8*)wfrag + (size_t)ci * 2048;
#pragma unroll
      for (int kt = 0; kt < 2; ++kt)
#pragma unroll
        for (int mi = 0; mi < 4; ++mi)
          areg[kt][mi] = wg[((oq * 4 + mi) * 2 + kt) * 64 + lane];

      // staging prefetch / commit for cb+1 (dbuf; commit phase n==7 is
      // barrier-separated from first read at phase n==8's sampling)
      if (n == 6 && cb < 3) {
#pragma unroll
        for (int k = 0; k < 15; ++k) {
          int e = tid + k * 512;
          int pl = e / 240, pos = e - pl * 240;
          int ry = pos >> 4, rx = pos & 15;
          int gy = h0 - 3 + ry, gx = w0 - 3 + rx;
          bool ok = (rx < 15 && gy >= 0 && gy < 64 && gx >= 0 && gx < 64);
          pr0[k] = 0.f;
          pr1[k] = 0.f;
          if (ok) {
            const float* p0 = xb + (size_t)((cb + 1) * 64 + pl * 2) * 4096;
            pr0[k] = p0[gy * 64 + gx];
            pr1[k] = p0[4096 + gy * 64 + gx];
          }
        }
      }
      if (n == 7 && cb < 3) {
#pragma unroll
        for (int k = 0; k < 15; ++k) {
          int e = tid + k * 512;
          s_xp[(cb + 1) & 1][e] =
              (unsigned int)f2bf(pr0[k]) | ((unsigned int)f2bf(pr1[k]) << 16);
        }
      }

      // sample chunk ci+1 -> colf[(ci+1)&1]
      if (ci + 1 < 36) {
        int nn = n + 1, cbn = cb;
        if (nn == 9) {
          nn = 0;
          cbn = cb + 1;
        }
        sample_chunk(s_xp[cbn & 1], nn, s_colf[(ci + 1) & 1], oct, lane, s_w4,
                     s_coff);
      }

      // MFMA chunk ci from colf[ci&1]
      const unsigned short* cf = s_colf[ci & 1];
#pragma unroll
      for (int kt = 0; kt < 2; ++kt) {
        short8 bfr[2];
#pragma unroll
        for (int tn = 0; tn < 2; ++tn)
          bfr[tn] =
              *(const short8*)&cf[(((nh * 2 + tn) * 2 + kt) * 64 + lane) * 8];
#pragma unroll
        for (int mi = 0; mi < 4; ++mi)
#pragma unroll
          for (int tn = 0; tn < 2; ++tn)
            acc[mi][tn] = __builtin_amdgcn_mfma_f32_16x16x32_bf16(
                areg[kt][mi], bfr[tn], acc[mi][tn], 0, 0, 0);
      }
      __syncthreads();
    }
  }

  // epilogue (R5-verified): C/D col=lane&15, row=quad*4+r
  int quad = lane >> 4, col = lane & 15;
#pragma unroll
  for (int mi = 0; mi < 4; ++mi)
#pragma unroll
    for (int tn = 0; tn < 2; ++tn) {
      int pxo = (nh * 2 + tn) * 16 + col;
      int h = h0 + (pxo >> 3), w = w0 + (pxo & 7);
#pragma unroll
      for (int r = 0; r < 4; ++r) {
        int o = oq * 64 + mi * 16 + quad * 4 + r;
        out[(((size_t)b * 256 + o) * 64 + h) * 64 + w] =
            acc[mi][tn][r] + bias[o];
      }
    }
}

extern "C" void kernel_launch(void* const* d_in, const int* in_sizes, int n_in,
                              void* d_out, int out_size, void* d_ws,
                              size_t ws_size, hipStream_t stream) {
  (void)in_sizes; (void)n_in; (void)out_size; (void)ws_size;
  const float* x        = (const float*)d_in[0];  // (4,256,64,64)
  const float* offset_w = (const float*)d_in[1];  // (18,256,3,3)
  const float* offset_b = (const float*)d_in[2];  // (18,)
  const float* deform_w = (const float*)d_in[3];  // (256,256,3,3)
  const float* deform_b = (const float*)d_in[4];  // (256,)
  float* out = (float*)d_out;

  float* off_buf = (float*)d_ws;                                // 294912 f
  unsigned short* wfrag = (unsigned short*)(off_buf + 294912);  // 589824 bf16

  hipMemsetAsync(off_buf, 0, 294912 * sizeof(float), stream);
  prep_kernel<<<288, 256, 0, stream>>>(deform_w, wfrag);
  offset_conv_valu<<<dim3(16, 4, 8), 256, 0, stream>>>(x, offset_w, off_buf);
  deform_kernel<<<dim3(64, 4), 512, 0, stream>>>(x, off_buf, offset_b, wfrag,
                                                 deform_b, out);
  hipMemcpyAsync(out + 4194304, deform_w, 589824 * sizeof(float),
                 hipMemcpyDeviceToDevice, stream);
}